// Round 1
// baseline (5370.544 us; speedup 1.0000x reference)
//
#include <hip/hip_runtime.h>

// LSTMCharacterPredictor — round 1: correct persistent-scan implementation.
// T=512 B=64 E=512 H=1024 V=256.
// Pipeline: cvt(f32->bf16) -> proj_table GEMM -> persistent LSTM scan (MFMA,
// flag-synced h broadcast) -> decode GEMM.

#define TT 512
#define BB 64
#define HH 1024
#define VV 256
#define EE 512

typedef __attribute__((ext_vector_type(8))) short bf16x8;
typedef __attribute__((ext_vector_type(4))) float f32x4;
typedef __attribute__((ext_vector_type(4))) int i32x4;
typedef __attribute__((ext_vector_type(4))) unsigned short u16x4;

static __device__ __forceinline__ unsigned short f2bf(float f) {
  union { float f; unsigned u; } x; x.f = f;
  unsigned r = x.u + 0x7fffu + ((x.u >> 16) & 1u);   // RNE
  return (unsigned short)(r >> 16);
}

// ---------------- f32 -> bf16 convert (vectorized) ----------------
__global__ void cvt_bf16(const float* __restrict__ s, unsigned short* __restrict__ d, int n4) {
  int i = blockIdx.x * blockDim.x + threadIdx.x;
  int st = gridDim.x * blockDim.x;
  for (; i < n4; i += st) {
    f32x4 v = *(const f32x4*)(s + 4l * i);
    u16x4 o;
    o.x = f2bf(v.x); o.y = f2bf(v.y); o.z = f2bf(v.z); o.w = f2bf(v.w);
    *(u16x4*)(d + 4l * i) = o;
  }
}

// ---------------- proj_table[256,4096] = enc[256,512] @ W_ih^T + b_ih + b_hh ----------------
__global__ __launch_bounds__(256) void proj_kernel(
    const unsigned short* __restrict__ A,    // enc bf16 [256][512]
    const unsigned short* __restrict__ Wi,   // W_ih bf16 [4096][512]
    const float* __restrict__ bih, const float* __restrict__ bhh,
    float* __restrict__ proj)                // [256][4096]
{
  __shared__ __align__(16) unsigned char Asm[64 * 128];   // [64 m][64 k] bf16, swizzled
  const int tid = threadIdx.x;
  const int w = tid >> 6;
  const int lane = tid & 63;
  const int ln = lane & 15, kg = lane >> 4;
  const int m0 = blockIdx.x * 64;            // 4 blocks
  const int nb = blockIdx.y * 256 + w * 64;  // 16 blocks.y, wave owns 64 n
  const int srow = tid >> 2, skq = tid & 3;

  f32x4 acc[4][4];
  for (int a = 0; a < 4; ++a) for (int b = 0; b < 4; ++b) acc[a][b] = (f32x4){0.f,0.f,0.f,0.f};

  for (int kc = 0; kc < 8; ++kc) {           // K=512 in chunks of 64
    {
      const unsigned short* src = A + (m0 + srow) * 512 + kc * 64 + skq * 16;
      unsigned base = (unsigned)(srow * 128 + skq * 32);
      unsigned sw = (unsigned)((srow & 7) << 4);
      *(i32x4*)(Asm + ((base) ^ sw))      = *(const i32x4*)(src);
      *(i32x4*)(Asm + ((base + 16) ^ sw)) = *(const i32x4*)(src + 8);
    }
    __syncthreads();
    for (int kk = 0; kk < 2; ++kk) {
      bf16x8 afr[4];
      for (int mi = 0; mi < 4; ++mi) {
        int row = mi * 16 + ln;
        unsigned off = (unsigned)(row * 128 + (kk * 32 + kg * 8) * 2);
        afr[mi] = *(const bf16x8*)(Asm + (off ^ ((unsigned)(row & 7) << 4)));
      }
      for (int ni = 0; ni < 4; ++ni) {
        const unsigned short* bp = Wi + (nb + ni * 16 + ln) * 512 + kc * 64 + kk * 32 + kg * 8;
        bf16x8 bfr = *(const bf16x8*)bp;      // B[k][n]=W[n][k]: k-contiguous in W row
        for (int mi = 0; mi < 4; ++mi)
          acc[mi][ni] = __builtin_amdgcn_mfma_f32_16x16x32_bf16(afr[mi], bfr, acc[mi][ni], 0, 0, 0);
      }
    }
    __syncthreads();
  }
  for (int ni = 0; ni < 4; ++ni) {
    int nn = nb + ni * 16 + ln;
    float bias = bih[nn] + bhh[nn];
    for (int mi = 0; mi < 4; ++mi) {
      int mr = m0 + mi * 16 + kg * 4;
      for (int r = 0; r < 4; ++r)
        proj[(mr + r) * 4096 + nn] = acc[mi][ni][r] + bias;
    }
  }
}

// ---------------- persistent LSTM scan ----------------
// 256 blocks x 256 thr. group g=blk>>6 owns batch [g*16,+16); block j=blk&63 owns
// hidden units [j*16,+16) (64 gate rows). W slice in LDS bf16 swizzled. Per step:
// wait group flags -> acquire fence -> stage h (2 K-halves) -> MFMA (wave w = gate
// type, 16x16 tile, K=1024) -> gate exchange via LDS -> per-thread c/h update ->
// publish h (device-scope atomics) + outs + flag.
#define SPIN_CAP (1 << 24)

__global__ __launch_bounds__(256) void scan_kernel(
    const unsigned short* __restrict__ Whh,   // bf16 [4096][1024]
    const float* __restrict__ proj,           // [256][4096]
    const int* __restrict__ ints,             // [512][64]
    const float* __restrict__ h0v,            // output0 [1024]
    const float* __restrict__ c0v,            // memory0 [1024]
    unsigned int* __restrict__ hbuf,          // u32 view [2][64][512]
    unsigned int* __restrict__ outs,          // u32 view of outs bf16 [512][64][1024]
    unsigned int* __restrict__ flags)         // [256]
{
  __shared__ __align__(16) unsigned char Wl[131072];  // [64 rows][1024 k] bf16 swz
  __shared__ __align__(16) unsigned char Hl[16384];   // [16 b][512 k] bf16 swz
  __shared__ float gatesm[4][16][16];                 // [gate][batch][unit]
  __shared__ __align__(16) unsigned short hpack[16][16];
  __shared__ int s_dead;

  const int tid = threadIdx.x;
  const int blk = blockIdx.x;
  const int g = blk >> 6;
  const int j = blk & 63;
  const int w = tid >> 6;
  const int lane = tid & 63;
  const int ln = lane & 15, kg = lane >> 4;

  if (tid == 0) s_dead = 0;

  // load W_hh slice: local row r = gate*16+u  <->  global row gate*1024 + j*16 + u
  {
    const int rl = tid >> 2, kq = tid & 3;
    const int gate = rl >> 4, ul = rl & 15;
    const unsigned short* src = Whh + (long)(gate * 1024 + j * 16 + ul) * 1024 + kq * 256;
    unsigned base = (unsigned)(rl * 2048 + kq * 512);
    unsigned sw = (unsigned)((rl & 7) << 4);
    for (int i = 0; i < 32; ++i)
      *(i32x4*)(Wl + ((base + i * 16) ^ sw)) = *(const i32x4*)(src + i * 8);
  }

  const int b = tid >> 4, u = tid & 15;
  const int uglob = j * 16 + u;
  const int bglob = g * 16 + b;
  float c = c0v[uglob];
  float hv = h0v[uglob];

  // publish version 0 (h0) + outs[0]
  hpack[b][u] = f2bf(hv);
  __syncthreads();
  if (tid < 128) {
    unsigned word = ((const unsigned*)hpack)[tid];
    int pb = tid >> 3, pq = tid & 7;
    int idx = (g * 16 + pb) * 512 + j * 8 + pq;
    __hip_atomic_store(&hbuf[idx], word, __ATOMIC_RELAXED, __HIP_MEMORY_SCOPE_AGENT);
    outs[idx] = word;
  }
  __syncthreads();   // drains vmcnt: h stores at LLC before flag
  if (tid == 0) __hip_atomic_store(&flags[blk], 1u, __ATOMIC_RELAXED, __HIP_MEMORY_SCOPE_AGENT);

  for (int t = 0; t < TT - 1; ++t) {
    // wait for all 64 producers of this group to have published version t
    if (tid < 64 && !s_dead) {
      unsigned target = (unsigned)(t + 1);
      int guard = 0;
      while (__hip_atomic_load(&flags[g * 64 + tid], __ATOMIC_RELAXED, __HIP_MEMORY_SCOPE_AGENT) < target) {
        if (++guard > SPIN_CAP) { s_dead = 1; break; }   // bounded: avoid wedging the GPU
      }
    }
    __syncthreads();
    __builtin_amdgcn_fence(__ATOMIC_ACQUIRE, "agent");   // inv L1/L2-stale before plain h loads

    f32x4 acc0 = (f32x4){0.f,0.f,0.f,0.f}, acc1 = (f32x4){0.f,0.f,0.f,0.f};
    const unsigned* hsrc = hbuf + (t & 1) * 32768;

    for (int half = 0; half < 2; ++half) {
      {  // stage h [16][512] bf16 into swizzled LDS
        int row = tid >> 4, kc = tid & 15;
        const unsigned* src = hsrc + (g * 16 + row) * 512 + half * 256 + kc * 16;
        unsigned base = (unsigned)(row * 1024 + kc * 64);
        unsigned sw = (unsigned)((row & 7) << 4);
        *(i32x4*)(Hl + ((base) ^ sw))      = *(const i32x4*)(src);
        *(i32x4*)(Hl + ((base + 16) ^ sw)) = *(const i32x4*)(src + 4);
        *(i32x4*)(Hl + ((base + 32) ^ sw)) = *(const i32x4*)(src + 8);
        *(i32x4*)(Hl + ((base + 48) ^ sw)) = *(const i32x4*)(src + 12);
      }
      __syncthreads();
      {  // wave w: gates[16 b][16 u] for gate-type w over this K-half
        unsigned swa = (unsigned)((ln & 7) << 4);
        int wrow = w * 16 + ln;
        unsigned swb = (unsigned)((wrow & 7) << 4);
        for (int kt = 0; kt < 16; kt += 2) {   // 2 accumulators for MFMA ILP
          int kb0 = kt * 32 + kg * 8;
          int kb1 = kb0 + 32;
          bf16x8 a0 = *(const bf16x8*)(Hl + (((unsigned)(ln * 1024 + kb0 * 2)) ^ swa));
          bf16x8 b0 = *(const bf16x8*)(Wl + (((unsigned)(wrow * 2048 + (half * 512 + kb0) * 2)) ^ swb));
          acc0 = __builtin_amdgcn_mfma_f32_16x16x32_bf16(a0, b0, acc0, 0, 0, 0);
          bf16x8 a1 = *(const bf16x8*)(Hl + (((unsigned)(ln * 1024 + kb1 * 2)) ^ swa));
          bf16x8 b1 = *(const bf16x8*)(Wl + (((unsigned)(wrow * 2048 + (half * 512 + kb1) * 2)) ^ swb));
          acc1 = __builtin_amdgcn_mfma_f32_16x16x32_bf16(a1, b1, acc1, 0, 0, 0);
        }
      }
      __syncthreads();   // Hl reuse / before gate exchange
    }
    {  // D layout: m=(lane>>4)*4+reg (batch), n=lane&15 (unit)  [m89-verified]
      f32x4 accs = acc0 + acc1;
      for (int r = 0; r < 4; ++r) gatesm[w][kg * 4 + r][ln] = accs[r];
    }
    __syncthreads();
    {  // per-thread LSTM cell update: thread (b,u)
      int vocab = ints[t * 64 + bglob];
      const float* pr = proj + (long)vocab * 4096 + uglob;
      float gi = gatesm[0][b][u] + pr[0];
      float gf = gatesm[1][b][u] + pr[1024];
      float gg = gatesm[2][b][u] + pr[2048];
      float go = gatesm[3][b][u] + pr[3072];
      float ii = 1.f / (1.f + __expf(-gi));
      float ff = 1.f / (1.f + __expf(-gf));
      float gt = tanhf(gg);
      float oo = 1.f / (1.f + __expf(-go));
      c = ff * c + ii * gt;
      hv = oo * tanhf(c);
      hpack[b][u] = f2bf(hv);
    }
    __syncthreads();
    if (tid < 128) {  // publish version t+1 (double-buffer slot (t+1)&1) + outs[t+1]
      unsigned word = ((const unsigned*)hpack)[tid];
      int pb = tid >> 3, pq = tid & 7;
      int idx = (g * 16 + pb) * 512 + j * 8 + pq;
      __hip_atomic_store(&hbuf[((t + 1) & 1) * 32768 + idx], word, __ATOMIC_RELAXED, __HIP_MEMORY_SCOPE_AGENT);
      outs[(t + 1) * 32768 + idx] = word;
    }
    __syncthreads();   // vmcnt drained -> h stores globally visible before flag
    if (tid == 0)
      __hip_atomic_store(&flags[blk], (unsigned)(t + 2), __ATOMIC_RELAXED, __HIP_MEMORY_SCOPE_AGENT);
  }
}

// ---------------- decode: out[32768,256] = outs_bf @ W_dec^T + b_dec ----------------
__global__ __launch_bounds__(256) void decode_kernel(
    const unsigned short* __restrict__ A,    // outs bf16 [32768][1024]
    const unsigned short* __restrict__ Wd,   // W_dec bf16 [256][1024]
    const float* __restrict__ bdec,
    float* __restrict__ out)                 // [32768][256]
{
  __shared__ __align__(16) unsigned char Asm[64 * 128];
  const int tid = threadIdx.x;
  const int w = tid >> 6;
  const int lane = tid & 63;
  const int ln = lane & 15, kg = lane >> 4;
  const int m0 = blockIdx.x * 64;
  const int nb = w * 64;                     // 4 waves cover N=256
  const int srow = tid >> 2, skq = tid & 3;

  f32x4 acc[4][4];
  for (int a = 0; a < 4; ++a) for (int b = 0; b < 4; ++b) acc[a][b] = (f32x4){0.f,0.f,0.f,0.f};

  for (int kc = 0; kc < 16; ++kc) {          // K=1024 in chunks of 64
    {
      const unsigned short* src = A + (m0 + srow) * 1024 + kc * 64 + skq * 16;
      unsigned base = (unsigned)(srow * 128 + skq * 32);
      unsigned sw = (unsigned)((srow & 7) << 4);
      *(i32x4*)(Asm + ((base) ^ sw))      = *(const i32x4*)(src);
      *(i32x4*)(Asm + ((base + 16) ^ sw)) = *(const i32x4*)(src + 8);
    }
    __syncthreads();
    for (int kk = 0; kk < 2; ++kk) {
      bf16x8 afr[4];
      for (int mi = 0; mi < 4; ++mi) {
        int row = mi * 16 + ln;
        unsigned off = (unsigned)(row * 128 + (kk * 32 + kg * 8) * 2);
        afr[mi] = *(const bf16x8*)(Asm + (off ^ ((unsigned)(row & 7) << 4)));
      }
      for (int ni = 0; ni < 4; ++ni) {
        const unsigned short* bp = Wd + (nb + ni * 16 + ln) * 1024 + kc * 64 + kk * 32 + kg * 8;
        bf16x8 bfr = *(const bf16x8*)bp;
        for (int mi = 0; mi < 4; ++mi)
          acc[mi][ni] = __builtin_amdgcn_mfma_f32_16x16x32_bf16(afr[mi], bfr, acc[mi][ni], 0, 0, 0);
      }
    }
    __syncthreads();
  }
  for (int ni = 0; ni < 4; ++ni) {
    int nn = nb + ni * 16 + ln;
    float bd = bdec[nn];
    for (int mi = 0; mi < 4; ++mi) {
      int mr = m0 + mi * 16 + kg * 4;
      for (int r = 0; r < 4; ++r)
        out[(mr + r) * 256 + nn] = acc[mi][ni][r] + bd;
    }
  }
}

// ---------------- host ----------------
extern "C" void kernel_launch(void* const* d_in, const int* in_sizes, int n_in,
                              void* d_out, int out_size, void* d_ws, size_t ws_size,
                              hipStream_t stream) {
  const int*   ints = (const int*)  d_in[0];
  const float* enc  = (const float*)d_in[1];
  const float* out0 = (const float*)d_in[2];
  const float* mem0 = (const float*)d_in[3];
  const float* Wih  = (const float*)d_in[4];
  const float* Whh  = (const float*)d_in[5];
  const float* bih  = (const float*)d_in[6];
  const float* bhh  = (const float*)d_in[7];
  const float* Wdec = (const float*)d_in[8];
  const float* bdec = (const float*)d_in[9];
  float* out = (float*)d_out;

  char* ws = (char*)d_ws;
  size_t off = 0;
  auto alloc = [&](size_t bytes) { char* p = ws + off; off += (bytes + 255) & ~(size_t)255; return p; };
  unsigned short* Whh_bf  = (unsigned short*)alloc(4096ull * 1024 * 2);   // 8 MB
  unsigned short* enc_bf  = (unsigned short*)alloc(256ull * 512 * 2);
  unsigned short* Wih_bf  = (unsigned short*)alloc(4096ull * 512 * 2);
  unsigned short* Wdec_bf = (unsigned short*)alloc(256ull * 1024 * 2);
  float*          proj    = (float*)alloc(256ull * 4096 * 4);             // 4 MB
  unsigned short* outs_bf = (unsigned short*)alloc(512ull * 64 * 1024 * 2); // 64 MB
  unsigned int*   hbuf    = (unsigned int*)alloc(2ull * 64 * 512 * 4);
  unsigned int*   flags   = (unsigned int*)alloc(256 * 4);
  // total ~85 MB of ws

  hipMemsetAsync(flags, 0, 256 * 4, stream);   // flag protocol reset each launch (replay-safe)

  cvt_bf16<<<512, 256, 0, stream>>>(Whh,  Whh_bf,  4096 * 1024 / 4);
  cvt_bf16<<<64,  256, 0, stream>>>(enc,  enc_bf,  256 * 512 / 4);
  cvt_bf16<<<256, 256, 0, stream>>>(Wih,  Wih_bf,  4096 * 512 / 4);
  cvt_bf16<<<64,  256, 0, stream>>>(Wdec, Wdec_bf, 256 * 1024 / 4);

  proj_kernel<<<dim3(4, 16), 256, 0, stream>>>(enc_bf, Wih_bf, bih, bhh, proj);

  {
    const unsigned short* a0 = Whh_bf;
    const float* a1 = proj;
    const int* a2 = ints;
    const float* a3 = out0;
    const float* a4 = mem0;
    unsigned int* a5 = hbuf;
    unsigned int* a6 = (unsigned int*)outs_bf;
    unsigned int* a7 = flags;
    void* args[] = { &a0, &a1, &a2, &a3, &a4, &a5, &a6, &a7 };
    hipError_t e = hipLaunchCooperativeKernel((const void*)scan_kernel,
                                              dim3(256), dim3(256), args, 0, stream);
    if (e != hipSuccess) {
      // fallback: plain launch. 256 blocks x 1 block/CU (152 KB LDS) => co-resident.
      scan_kernel<<<256, 256, 0, stream>>>(Whh_bf, proj, ints, out0, mem0,
                                           hbuf, (unsigned int*)outs_bf, flags);
    }
  }

  decode_kernel<<<512, 256, 0, stream>>>(outs_bf, Wdec_bf, bdec, out);
}

// Round 2
// 1910.336 us; speedup vs baseline: 2.8113x; 2.8113x over previous
//
#include <hip/hip_runtime.h>

// LSTMCharacterPredictor — round 2: latency-lean persistent scan.
// T=512 B=64 E=512 H=1024 V=256.
// R1 post-mortem: 10.4us/step, latency-bound. Fixes: (1) no acquire fence
// (was buffer_inv'ing L2 every step) -> sc0/sc1-flagged loads/stores instead;
// (2) W_hh fragments in VGPRs (K-split over 4 waves) -> no LDS W reads (was
// 2.4e8 bank-conflict cycles); (3) h A-frags loaded directly global->reg
// (no LDS staging); (4) per-wave flags -> 1 barrier/step (was 6).

#define TT 512
#define BB 64
#define HH 1024
#define VV 256
#define EE 512

typedef __attribute__((ext_vector_type(8))) short bf16x8;
typedef __attribute__((ext_vector_type(4))) float f32x4;
typedef __attribute__((ext_vector_type(4))) int i32x4;
typedef __attribute__((ext_vector_type(4))) unsigned short u16x4;

static __device__ __forceinline__ unsigned short f2bf(float f) {
  union { float f; unsigned u; } x; x.f = f;
  unsigned r = x.u + 0x7fffu + ((x.u >> 16) & 1u);   // RNE
  return (unsigned short)(r >> 16);
}

// ---------------- f32 -> bf16 convert (vectorized) ----------------
__global__ void cvt_bf16(const float* __restrict__ s, unsigned short* __restrict__ d, int n4) {
  int i = blockIdx.x * blockDim.x + threadIdx.x;
  int st = gridDim.x * blockDim.x;
  for (; i < n4; i += st) {
    f32x4 v = *(const f32x4*)(s + 4l * i);
    u16x4 o;
    o.x = f2bf(v.x); o.y = f2bf(v.y); o.z = f2bf(v.z); o.w = f2bf(v.w);
    *(u16x4*)(d + 4l * i) = o;
  }
}

// ---------------- proj_table[256,4096] = enc[256,512] @ W_ih^T + b_ih + b_hh ----------------
__global__ __launch_bounds__(256) void proj_kernel(
    const unsigned short* __restrict__ A,    // enc bf16 [256][512]
    const unsigned short* __restrict__ Wi,   // W_ih bf16 [4096][512]
    const float* __restrict__ bih, const float* __restrict__ bhh,
    float* __restrict__ proj)                // [256][4096]
{
  __shared__ __align__(16) unsigned char Asm[64 * 128];   // [64 m][64 k] bf16, swizzled
  const int tid = threadIdx.x;
  const int w = tid >> 6;
  const int lane = tid & 63;
  const int ln = lane & 15, kg = lane >> 4;
  const int m0 = blockIdx.x * 64;            // 4 blocks
  const int nb = blockIdx.y * 256 + w * 64;  // 16 blocks.y, wave owns 64 n
  const int srow = tid >> 2, skq = tid & 3;

  f32x4 acc[4][4];
  for (int a = 0; a < 4; ++a) for (int b = 0; b < 4; ++b) acc[a][b] = (f32x4){0.f,0.f,0.f,0.f};

  for (int kc = 0; kc < 8; ++kc) {           // K=512 in chunks of 64
    {
      const unsigned short* src = A + (m0 + srow) * 512 + kc * 64 + skq * 16;
      unsigned base = (unsigned)(srow * 128 + skq * 32);
      unsigned sw = (unsigned)((srow & 7) << 4);
      *(i32x4*)(Asm + ((base) ^ sw))      = *(const i32x4*)(src);
      *(i32x4*)(Asm + ((base + 16) ^ sw)) = *(const i32x4*)(src + 8);
    }
    __syncthreads();
    for (int kk = 0; kk < 2; ++kk) {
      bf16x8 afr[4];
      for (int mi = 0; mi < 4; ++mi) {
        int row = mi * 16 + ln;
        unsigned off = (unsigned)(row * 128 + (kk * 32 + kg * 8) * 2);
        afr[mi] = *(const bf16x8*)(Asm + (off ^ ((unsigned)(row & 7) << 4)));
      }
      for (int ni = 0; ni < 4; ++ni) {
        const unsigned short* bp = Wi + (nb + ni * 16 + ln) * 512 + kc * 64 + kk * 32 + kg * 8;
        bf16x8 bfr = *(const bf16x8*)bp;
        for (int mi = 0; mi < 4; ++mi)
          acc[mi][ni] = __builtin_amdgcn_mfma_f32_16x16x32_bf16(afr[mi], bfr, acc[mi][ni], 0, 0, 0);
      }
    }
    __syncthreads();
  }
  for (int ni = 0; ni < 4; ++ni) {
    int nn = nb + ni * 16 + ln;
    float bias = bih[nn] + bhh[nn];
    for (int mi = 0; mi < 4; ++mi) {
      int mr = m0 + mi * 16 + kg * 4;
      for (int r = 0; r < 4; ++r)
        proj[(mr + r) * 4096 + nn] = acc[mi][ni][r] + bias;
    }
  }
}

// ---------------- persistent LSTM scan ----------------
// 256 blocks x 256 thr. group g=blk>>6 owns batches [g*16,+16); block j=blk&63
// owns hidden units [j*16,+16) (64 gate rows). Wave w holds B-frags (W_hh) for
// all 4 gates over K-slice [w*256,+256) in VGPRs. Per step: prefetch proj/ints
// -> spin on 256 per-wave flags -> A-frags direct global sc0sc1 -> 32 MFMA
// (4 indep chains) -> gatesm LDS exchange (1 barrier) -> elementwise ->
// global_store_short sc0sc1 into outs[t+1] -> vmcnt drain -> per-wave flag.
#define SPIN_CAP (1 << 16)

__global__ __launch_bounds__(256, 1) void scan_kernel(
    const unsigned short* __restrict__ Whh,   // bf16 [4096][1024]
    const float* __restrict__ proj,           // [256][4096]
    const int* __restrict__ ints,             // [512][64]
    const float* __restrict__ h0v,            // output0 [1024]
    const float* __restrict__ c0v,            // memory0 [1024]
    unsigned short* __restrict__ outs,        // bf16 [512][64][1024] == h history
    unsigned int* __restrict__ flags)         // [4 g][4 w][64 j]
{
  __shared__ float gatesm[4][4][16][16];      // [w][gi][b][u] f32 partials (16 KB)

  const int tid = threadIdx.x;
  const int blk = blockIdx.x;
  const int g = blk >> 6, j = blk & 63;
  const int w = tid >> 6, lane = tid & 63;
  const int ln = lane & 15, kg = lane >> 4;
  const int b = tid >> 4, u = tid & 15;
  const int uglob = j * 16 + u;
  const int bglob = g * 16 + b;

  // W_hh B-fragments in registers: gate gi row (gi*1024 + j*16 + ln),
  // k = w*256 + kt*32 + kg*8 .. +8  (matches A-frag k order -> consistent).
  bf16x8 bw[4][8];
#pragma unroll
  for (int gi = 0; gi < 4; ++gi)
#pragma unroll
    for (int kt = 0; kt < 8; ++kt)
      bw[gi][kt] = *(const bf16x8*)(Whh + (size_t)(gi * 1024 + j * 16 + ln) * 1024
                                        + w * 256 + kt * 32 + kg * 8);

  float c = c0v[uglob];

  // publish h0 -> outs[0]; per-wave flag
  {
    unsigned hb = f2bf(h0v[uglob]);
    unsigned short* op = outs + (size_t)bglob * 1024 + uglob;
    asm volatile("global_store_short %0, %1, off sc0 sc1" :: "v"(op), "v"(hb) : "memory");
    asm volatile("s_waitcnt vmcnt(0)" ::: "memory");
    if (lane == 0)
      __hip_atomic_store(&flags[(g * 4 + w) * 64 + j], 1u,
                         __ATOMIC_RELAXED, __HIP_MEMORY_SCOPE_AGENT);
  }

  const unsigned int* fb = flags + g * 256;   // this group's 256 per-wave flags

  for (int t = 0; t < TT - 1; ++t) {
    // ---- prefetch (independent of h; overlaps spin) ----
    int vocab = ints[t * 64 + bglob];
    const float* pp = proj + (size_t)vocab * 4096 + uglob;
    float pr0 = pp[0];
    float pr1 = pp[1024];
    float pr2 = pp[2048];
    float pr3 = pp[3072];

    // ---- spin: all lanes poll all 256 producer-wave flags of this group ----
    {
      unsigned tgt = (unsigned)(t + 1);
      int guard = 0;
      while (true) {
        unsigned f0 = __hip_atomic_load(fb +       lane, __ATOMIC_RELAXED, __HIP_MEMORY_SCOPE_AGENT);
        unsigned f1 = __hip_atomic_load(fb +  64 + lane, __ATOMIC_RELAXED, __HIP_MEMORY_SCOPE_AGENT);
        unsigned f2 = __hip_atomic_load(fb + 128 + lane, __ATOMIC_RELAXED, __HIP_MEMORY_SCOPE_AGENT);
        unsigned f3 = __hip_atomic_load(fb + 192 + lane, __ATOMIC_RELAXED, __HIP_MEMORY_SCOPE_AGENT);
        unsigned m0 = f0 < f1 ? f0 : f1;
        unsigned m1 = f2 < f3 ? f2 : f3;
        unsigned mm = m0 < m1 ? m0 : m1;
        if (__all((int)(mm >= tgt))) break;
        if (++guard > SPIN_CAP) break;        // bounded: never wedge the GPU
      }
    }
    asm volatile("" ::: "memory");            // no hoisting loads above the spin

    // ---- A-frags: h(t) rows, direct global->reg, coherent-at-L3 ----
    i32x4 a[8];
    const unsigned short* ab = outs + (size_t)(t * 64 + g * 16 + ln) * 1024
                                    + w * 256 + kg * 8;
#define LOADA(i, off_lit) \
    asm volatile("global_load_dwordx4 %0, %1, off offset:" off_lit " sc0 sc1" \
                 : "=v"(a[i]) : "v"(ab) : "memory")
    LOADA(0, "0");   LOADA(1, "64");  LOADA(2, "128"); LOADA(3, "192");
    LOADA(4, "256"); LOADA(5, "320"); LOADA(6, "384"); LOADA(7, "448");
#undef LOADA
    asm volatile("s_waitcnt vmcnt(0)" ::: "memory");
    __builtin_amdgcn_sched_barrier(0);        // rule 18: don't hoist MFMA past wait

    // ---- 32 MFMAs, 4 independent chains (one per gate) ----
    f32x4 ac0 = (f32x4){0.f,0.f,0.f,0.f}, ac1 = ac0, ac2 = ac0, ac3 = ac0;
#pragma unroll
    for (int kt = 0; kt < 8; ++kt) {
      union { i32x4 i; bf16x8 h; } av; av.i = a[kt];
      ac0 = __builtin_amdgcn_mfma_f32_16x16x32_bf16(av.h, bw[0][kt], ac0, 0, 0, 0);
      ac1 = __builtin_amdgcn_mfma_f32_16x16x32_bf16(av.h, bw[1][kt], ac1, 0, 0, 0);
      ac2 = __builtin_amdgcn_mfma_f32_16x16x32_bf16(av.h, bw[2][kt], ac2, 0, 0, 0);
      ac3 = __builtin_amdgcn_mfma_f32_16x16x32_bf16(av.h, bw[3][kt], ac3, 0, 0, 0);
    }

    // ---- cross-wave K-reduction via LDS (the one barrier per step) ----
    // D layout: n(unit)=lane&15, m(batch)=(lane>>4)*4+r  [m89-verified]
#pragma unroll
    for (int r = 0; r < 4; ++r) {
      gatesm[w][0][kg * 4 + r][ln] = ac0[r];
      gatesm[w][1][kg * 4 + r][ln] = ac1[r];
      gatesm[w][2][kg * 4 + r][ln] = ac2[r];
      gatesm[w][3][kg * 4 + r][ln] = ac3[r];
    }
    __syncthreads();

    // ---- elementwise cell update: thread (b,u) ----
    float gi_ = pr0, gf_ = pr1, gg_ = pr2, go_ = pr3;
#pragma unroll
    for (int ww = 0; ww < 4; ++ww) {
      gi_ += gatesm[ww][0][b][u];
      gf_ += gatesm[ww][1][b][u];
      gg_ += gatesm[ww][2][b][u];
      go_ += gatesm[ww][3][b][u];
    }
    float ii = __builtin_amdgcn_rcpf(1.f + __expf(-gi_));
    float ff = __builtin_amdgcn_rcpf(1.f + __expf(-gf_));
    float gt = 1.f - 2.f * __builtin_amdgcn_rcpf(1.f + __expf(2.f * gg_));
    float oo = __builtin_amdgcn_rcpf(1.f + __expf(-go_));
    c = ff * c + ii * gt;
    float hv = oo * (1.f - 2.f * __builtin_amdgcn_rcpf(1.f + __expf(2.f * c)));

    // ---- publish h(t+1) into outs[t+1]; per-wave vmcnt drain + flag ----
    {
      unsigned hb = f2bf(hv);
      unsigned short* op = outs + (size_t)((t + 1) * 64 + bglob) * 1024 + uglob;
      asm volatile("global_store_short %0, %1, off sc0 sc1" :: "v"(op), "v"(hb) : "memory");
      asm volatile("s_waitcnt vmcnt(0)" ::: "memory");
      if (lane == 0)
        __hip_atomic_store(&flags[(g * 4 + w) * 64 + j], (unsigned)(t + 2),
                           __ATOMIC_RELAXED, __HIP_MEMORY_SCOPE_AGENT);
    }
    // NOTE: no second barrier — next step's gatesm writes can only happen after
    // this block's own 4 wave-flags reach t+2 (spin), which data-depends on the
    // gatesm reads above. Write-after-read hazard is subsumed by the protocol.
  }
}

// ---------------- decode: out[32768,256] = outs_bf @ W_dec^T + b_dec ----------------
__global__ __launch_bounds__(256) void decode_kernel(
    const unsigned short* __restrict__ A,    // outs bf16 [32768][1024]
    const unsigned short* __restrict__ Wd,   // W_dec bf16 [256][1024]
    const float* __restrict__ bdec,
    float* __restrict__ out)                 // [32768][256]
{
  __shared__ __align__(16) unsigned char Asm[64 * 128];
  const int tid = threadIdx.x;
  const int w = tid >> 6;
  const int lane = tid & 63;
  const int ln = lane & 15, kg = lane >> 4;
  const int m0 = blockIdx.x * 64;
  const int nb = w * 64;                     // 4 waves cover N=256
  const int srow = tid >> 2, skq = tid & 3;

  f32x4 acc[4][4];
  for (int a = 0; a < 4; ++a) for (int b = 0; b < 4; ++b) acc[a][b] = (f32x4){0.f,0.f,0.f,0.f};

  for (int kc = 0; kc < 16; ++kc) {          // K=1024 in chunks of 64
    {
      const unsigned short* src = A + (m0 + srow) * 1024 + kc * 64 + skq * 16;
      unsigned base = (unsigned)(srow * 128 + skq * 32);
      unsigned sw = (unsigned)((srow & 7) << 4);
      *(i32x4*)(Asm + ((base) ^ sw))      = *(const i32x4*)(src);
      *(i32x4*)(Asm + ((base + 16) ^ sw)) = *(const i32x4*)(src + 8);
    }
    __syncthreads();
    for (int kk = 0; kk < 2; ++kk) {
      bf16x8 afr[4];
      for (int mi = 0; mi < 4; ++mi) {
        int row = mi * 16 + ln;
        unsigned off = (unsigned)(row * 128 + (kk * 32 + kg * 8) * 2);
        afr[mi] = *(const bf16x8*)(Asm + (off ^ ((unsigned)(row & 7) << 4)));
      }
      for (int ni = 0; ni < 4; ++ni) {
        const unsigned short* bp = Wd + (nb + ni * 16 + ln) * 1024 + kc * 64 + kk * 32 + kg * 8;
        bf16x8 bfr = *(const bf16x8*)bp;
        for (int mi = 0; mi < 4; ++mi)
          acc[mi][ni] = __builtin_amdgcn_mfma_f32_16x16x32_bf16(afr[mi], bfr, acc[mi][ni], 0, 0, 0);
      }
    }
    __syncthreads();
  }
  for (int ni = 0; ni < 4; ++ni) {
    int nn = nb + ni * 16 + ln;
    float bd = bdec[nn];
    for (int mi = 0; mi < 4; ++mi) {
      int mr = m0 + mi * 16 + kg * 4;
      for (int r = 0; r < 4; ++r)
        out[(mr + r) * 256 + nn] = acc[mi][ni][r] + bd;
    }
  }
}

// ---------------- host ----------------
extern "C" void kernel_launch(void* const* d_in, const int* in_sizes, int n_in,
                              void* d_out, int out_size, void* d_ws, size_t ws_size,
                              hipStream_t stream) {
  const int*   ints = (const int*)  d_in[0];
  const float* enc  = (const float*)d_in[1];
  const float* out0 = (const float*)d_in[2];
  const float* mem0 = (const float*)d_in[3];
  const float* Wih  = (const float*)d_in[4];
  const float* Whh  = (const float*)d_in[5];
  const float* bih  = (const float*)d_in[6];
  const float* bhh  = (const float*)d_in[7];
  const float* Wdec = (const float*)d_in[8];
  const float* bdec = (const float*)d_in[9];
  float* out = (float*)d_out;

  char* ws = (char*)d_ws;
  size_t off = 0;
  auto alloc = [&](size_t bytes) { char* p = ws + off; off += (bytes + 255) & ~(size_t)255; return p; };
  unsigned short* Whh_bf  = (unsigned short*)alloc(4096ull * 1024 * 2);     // 8 MB
  unsigned short* enc_bf  = (unsigned short*)alloc(256ull * 512 * 2);
  unsigned short* Wih_bf  = (unsigned short*)alloc(4096ull * 512 * 2);      // 4 MB
  unsigned short* Wdec_bf = (unsigned short*)alloc(256ull * 1024 * 2);
  float*          proj    = (float*)alloc(256ull * 4096 * 4);               // 4 MB
  unsigned short* outs_bf = (unsigned short*)alloc(512ull * 64 * 1024 * 2); // 64 MB
  unsigned int*   flags   = (unsigned int*)alloc(1024 * 4);                 // 4 KB
  // total ~81 MB of ws

  hipMemsetAsync(flags, 0, 1024 * 4, stream);   // protocol reset (replay-safe)

  cvt_bf16<<<512, 256, 0, stream>>>(Whh,  Whh_bf,  4096 * 1024 / 4);
  cvt_bf16<<<64,  256, 0, stream>>>(enc,  enc_bf,  256 * 512 / 4);
  cvt_bf16<<<256, 256, 0, stream>>>(Wih,  Wih_bf,  4096 * 512 / 4);
  cvt_bf16<<<64,  256, 0, stream>>>(Wdec, Wdec_bf, 256 * 1024 / 4);

  proj_kernel<<<dim3(4, 16), 256, 0, stream>>>(enc_bf, Wih_bf, bih, bhh, proj);

  {
    const unsigned short* a0 = Whh_bf;
    const float* a1 = proj;
    const int* a2 = ints;
    const float* a3 = out0;
    const float* a4 = mem0;
    unsigned short* a5 = outs_bf;
    unsigned int* a6 = flags;
    void* args[] = { &a0, &a1, &a2, &a3, &a4, &a5, &a6 };
    hipError_t e = hipLaunchCooperativeKernel((const void*)scan_kernel,
                                              dim3(256), dim3(256), args, 0, stream);
    if (e != hipSuccess) {
      // fallback: plain launch; 256 blocks all co-resident (16 KB LDS, 1+ blk/CU)
      scan_kernel<<<256, 256, 0, stream>>>(Whh_bf, proj, ints, out0, mem0,
                                           outs_bf, flags);
    }
  }

  decode_kernel<<<512, 256, 0, stream>>>(outs_bf, Wdec_bf, bdec, out);
}